// Round 6
// baseline (212.036 us; speedup 1.0000x reference)
//
#include <hip/hip_runtime.h>

typedef float nf4 __attribute__((ext_vector_type(4)));

// Cell2Tissue: conv3x3(cell) -> avgpool4 -> add into per-sample ROI of tissue -> broadcast x4.
//
// Pipeline (4 kernels):
//  k_wt    : wT2[ci][k][c] = w[c][ci][k]   (590 KB, once; scattered reads, coalesced writes)
//  k_gemm  : per (pooled-row i, split): 6 cell rows -> vertical 4-sums -> box row-triple in
//            LDS -> FMA vs coalesced-staged wT2 slice. part[s][c][i*64+j].
//  k_avgfin: avg = bias + (sum_s part[s]) / 16
//  k_out   : block owns ONE broadcast copy b = bid&3; single contiguous store stream;
//            tissue chunk shared by 4 sibling blocks via L2/MALL.
//
// ws layout (bytes): part @0 (33,554,432) | avg @33,554,432 (2,097,152) | wT2 @35,651,584 (589,824)

#define NSPLIT 16
#define CIPS   8          // input channels per split

__global__ __launch_bounds__(256) void k_wt(const float* __restrict__ w,
                                            float* __restrict__ wT2) {
    int idx = blockIdx.x * 256 + threadIdx.x;          // 147456 = 128ci * 9k * 128c
    int c  = idx & 127;
    int k  = (idx >> 7) % 9;
    int ci = idx / 1152;
    wT2[idx] = w[(size_t)c * 1152 + ci * 9 + k];
}

__global__ __launch_bounds__(256) void k_gemm(const float* __restrict__ cell,
                                              const float* __restrict__ wT2,
                                              float* __restrict__ part) {
    __shared__ float vs[3][260];   // vertical 4-sums; index = cell col + 1 (cols -1..257)
    __shared__ float bx[3][256];   // box rows yy = 4i+dy
    __shared__ float wl[1152];     // wl[k*128 + c] = w[c][ci][k]
    int i     = blockIdx.x;        // pooled row 0..63
    int split = blockIdx.y;        // 0..15
    int tid = threadIdx.x;
    int cg  = tid & 31;            // out-channel group: c = 4*cg + a
    int pg  = tid >> 5;            // position group: j = 8*pg + p

    if (tid < 9) {                 // zero halo slots of vs once
        int dy = tid / 3, q = tid % 3;
        vs[dy][q == 0 ? 0 : 256 + q] = 0.f;   // slots 0, 257, 258
    }

    float acc[4][8];
#pragma unroll
    for (int a = 0; a < 4; ++a)
#pragma unroll
        for (int p = 0; p < 8; ++p) acc[a][p] = 0.f;

    int r0 = 4 * i - 1;
    for (int t = 0; t < CIPS; ++t) {
        int ci = split * CIPS + t;
        const float* base = cell + (size_t)ci * 65536;
        float cr[6];
#pragma unroll
        for (int r = 0; r < 6; ++r) {
            int row = r0 + r;
            cr[r] = ((unsigned)row < 256u) ? base[row * 256 + tid] : 0.f;
        }
        __syncthreads();                       // prior iter done reading wl / vs
        vs[0][tid + 1] = cr[0] + cr[1] + cr[2] + cr[3];
        vs[1][tid + 1] = cr[1] + cr[2] + cr[3] + cr[4];
        vs[2][tid + 1] = cr[2] + cr[3] + cr[4] + cr[5];
        const float* wsrc = wT2 + (size_t)ci * 1152;   // coalesced, L2-resident
#pragma unroll
        for (int s = 0; s < 5; ++s) {
            int q = tid + 256 * s;
            if (q < 1152) wl[q] = wsrc[q];
        }
        __syncthreads();                       // vs + wl visible
#pragma unroll
        for (int dy = 0; dy < 3; ++dy)
            bx[dy][tid] = vs[dy][tid] + vs[dy][tid + 1] + vs[dy][tid + 2] + vs[dy][tid + 3];
        __syncthreads();                       // bx visible

        nf4 wv[9];
#pragma unroll
        for (int k = 0; k < 9; ++k)
            wv[k] = *(const nf4*)&wl[k * 128 + 4 * cg];
#pragma unroll
        for (int p = 0; p < 8; ++p) {
            int j = 8 * pg + p;
            nf4 b0 = *(const nf4*)&bx[0][4 * j];
            nf4 b1 = *(const nf4*)&bx[1][4 * j];
            nf4 b2 = *(const nf4*)&bx[2][4 * j];
#pragma unroll
            for (int a = 0; a < 4; ++a) {
                float sm = acc[a][p];
                sm = fmaf(wv[0][a], b0[0], sm);
                sm = fmaf(wv[1][a], b0[1], sm);
                sm = fmaf(wv[2][a], b0[2], sm);
                sm = fmaf(wv[3][a], b1[0], sm);
                sm = fmaf(wv[4][a], b1[1], sm);
                sm = fmaf(wv[5][a], b1[2], sm);
                sm = fmaf(wv[6][a], b2[0], sm);
                sm = fmaf(wv[7][a], b2[1], sm);
                sm = fmaf(wv[8][a], b2[2], sm);
                acc[a][p] = sm;
            }
        }
    }

    float* dst = part + (size_t)split * 524288;
#pragma unroll
    for (int a = 0; a < 4; ++a) {
        int c = 4 * cg + a;
        float* row = dst + (size_t)c * 4096 + i * 64 + 8 * pg;
        float4 lo = make_float4(acc[a][0], acc[a][1], acc[a][2], acc[a][3]);
        float4 hi = make_float4(acc[a][4], acc[a][5], acc[a][6], acc[a][7]);
        *(float4*)(row)     = lo;
        *(float4*)(row + 4) = hi;
    }
}

__global__ __launch_bounds__(256) void k_avgfin(const float* __restrict__ part,
                                                const float* __restrict__ bias,
                                                float* __restrict__ avg) {
    int idx4 = blockIdx.x * 256 + threadIdx.x;         // < 131072 float4s
    int c = idx4 >> 10;
    nf4 s = {0.f, 0.f, 0.f, 0.f};
#pragma unroll
    for (int sp = 0; sp < NSPLIT; ++sp)
        s += *(const nf4*)(part + (size_t)sp * 524288 + (size_t)idx4 * 4);
    nf4 o = s * 0.0625f + bias[c];
    *(nf4*)(avg + (size_t)idx4 * 4) = o;
}

// One copy per block: b = bid&3 (siblings adjacent in dispatch -> shared tissue chunk via
// MALL). Each block: 4 chunks x (plain 16B load + ROI add + nt 16B store), single stream.
__global__ __launch_bounds__(256) void k_out(const float* __restrict__ tissue,
                                             const float* __restrict__ avg,
                                             const int* __restrict__ loc,
                                             float* __restrict__ out) {
    int bid = blockIdx.x, tid = threadIdx.x;
    int b     = bid & 3;
    int group = bid >> 2;                              // 0..8191
    int base4 = group * 1024;                          // first float4 index of this block
    int j = base4 >> 21;                               // block-uniform -> s_load
    int c = (base4 >> 14) & 127;                       // block-uniform (1024 | 16384)
    int sh = (loc[2 * j + 1] >> 2) - 32;
    int sw = (loc[2 * j]     >> 2) - 32;
    const float* ar0 = avg + c * 4096;
    float* outb = out + (size_t)b * 33554432;

#pragma unroll
    for (int u = 0; u < 4; ++u) {
        int idx4 = base4 + u * 256 + tid;
        size_t f = (size_t)idx4 * 4;
        nf4 v = *(const nf4*)(tissue + f);             // allocating load: siblings hit MALL
        int h  = (idx4 >> 6) & 255;
        int ah = h - sh;
        if ((unsigned)ah < 64u) {
            const float* ar = ar0 + ah * 64;
            int aw = ((idx4 & 63) << 2) - sw;
            if ((unsigned)(aw    ) < 64u) v[0] += ar[aw];
            if ((unsigned)(aw + 1) < 64u) v[1] += ar[aw + 1];
            if ((unsigned)(aw + 2) < 64u) v[2] += ar[aw + 2];
            if ((unsigned)(aw + 3) < 64u) v[3] += ar[aw + 3];
        }
        __builtin_nontemporal_store(v, (nf4*)(outb + f));
    }
}

extern "C" void kernel_launch(void* const* d_in, const int* in_sizes, int n_in,
                              void* d_out, int out_size, void* d_ws, size_t ws_size,
                              hipStream_t stream) {
    const float* tissue = (const float*)d_in[0];
    const float* cell   = (const float*)d_in[1];
    const int*   loc    = (const int*)d_in[2];
    const float* w      = (const float*)d_in[3];
    const float* bias   = (const float*)d_in[4];
    float* out = (float*)d_out;

    char* wsb = (char*)d_ws;
    float* part = (float*)(wsb);
    float* avg  = (float*)(wsb + 33554432);
    float* wT2  = (float*)(wsb + 35651584);

    k_wt<<<576, 256, 0, stream>>>(w, wT2);
    k_gemm<<<dim3(64, NSPLIT), 256, 0, stream>>>(cell, wT2, part);
    k_avgfin<<<512, 256, 0, stream>>>(part, bias, avg);
    k_out<<<32768, 256, 0, stream>>>(tissue, avg, loc, out);
}

// Round 7
// 189.093 us; speedup vs baseline: 1.1213x; 1.1213x over previous
//
#include <hip/hip_runtime.h>

typedef float nf4 __attribute__((ext_vector_type(4)));

// Cell2Tissue: conv3x3(cell) -> avgpool4 -> add into per-sample ROI of tissue -> broadcast x4.
//
// Pipeline (4 kernels):
//  k_wt    : wT2[ci][k][c] = w[c][ci][k]   (590 KB, once)
//  k_gemm  : per (pooled-row i, split): 6 cell rows -> vertical 4-sums -> box row-triple in
//            LDS -> FMA vs coalesced-staged wT2 slice. part[s][c][i*64+j].
//  k_avgfin: avg = bias + (sum_s part[s]) / 16
//  k_out   : read-once-write-4copies, deep-batched: per thread 4 float4 loads ->
//            ROI add -> 16 nt stores grouped per copy (16KB bursts per stream per wave).
//
// ws layout (bytes): part @0 (33,554,432) | avg @33,554,432 (2,097,152) | wT2 @35,651,584 (589,824)

#define NSPLIT 16
#define CIPS   8          // input channels per split

__global__ __launch_bounds__(256) void k_wt(const float* __restrict__ w,
                                            float* __restrict__ wT2) {
    int idx = blockIdx.x * 256 + threadIdx.x;          // 147456 = 128ci * 9k * 128c
    int c  = idx & 127;
    int k  = (idx >> 7) % 9;
    int ci = idx / 1152;
    wT2[idx] = w[(size_t)c * 1152 + ci * 9 + k];
}

__global__ __launch_bounds__(256) void k_gemm(const float* __restrict__ cell,
                                              const float* __restrict__ wT2,
                                              float* __restrict__ part) {
    __shared__ float vs[3][260];   // vertical 4-sums; index = cell col + 1 (cols -1..257)
    __shared__ float bx[3][256];   // box rows yy = 4i+dy
    __shared__ float wl[1152];     // wl[k*128 + c] = w[c][ci][k]
    int i     = blockIdx.x;        // pooled row 0..63
    int split = blockIdx.y;        // 0..15
    int tid = threadIdx.x;
    int cg  = tid & 31;            // out-channel group: c = 4*cg + a
    int pg  = tid >> 5;            // position group: j = 8*pg + p

    if (tid < 9) {                 // zero halo slots of vs once
        int dy = tid / 3, q = tid % 3;
        vs[dy][q == 0 ? 0 : 256 + q] = 0.f;   // slots 0, 257, 258
    }

    float acc[4][8];
#pragma unroll
    for (int a = 0; a < 4; ++a)
#pragma unroll
        for (int p = 0; p < 8; ++p) acc[a][p] = 0.f;

    int r0 = 4 * i - 1;
    for (int t = 0; t < CIPS; ++t) {
        int ci = split * CIPS + t;
        const float* base = cell + (size_t)ci * 65536;
        float cr[6];
#pragma unroll
        for (int r = 0; r < 6; ++r) {
            int row = r0 + r;
            cr[r] = ((unsigned)row < 256u) ? base[row * 256 + tid] : 0.f;
        }
        __syncthreads();                       // prior iter done reading wl / vs
        vs[0][tid + 1] = cr[0] + cr[1] + cr[2] + cr[3];
        vs[1][tid + 1] = cr[1] + cr[2] + cr[3] + cr[4];
        vs[2][tid + 1] = cr[2] + cr[3] + cr[4] + cr[5];
        const float* wsrc = wT2 + (size_t)ci * 1152;   // coalesced, L2-resident
#pragma unroll
        for (int s = 0; s < 5; ++s) {
            int q = tid + 256 * s;
            if (q < 1152) wl[q] = wsrc[q];
        }
        __syncthreads();                       // vs + wl visible
#pragma unroll
        for (int dy = 0; dy < 3; ++dy)
            bx[dy][tid] = vs[dy][tid] + vs[dy][tid + 1] + vs[dy][tid + 2] + vs[dy][tid + 3];
        __syncthreads();                       // bx visible

        nf4 wv[9];
#pragma unroll
        for (int k = 0; k < 9; ++k)
            wv[k] = *(const nf4*)&wl[k * 128 + 4 * cg];
#pragma unroll
        for (int p = 0; p < 8; ++p) {
            int j = 8 * pg + p;
            nf4 b0 = *(const nf4*)&bx[0][4 * j];
            nf4 b1 = *(const nf4*)&bx[1][4 * j];
            nf4 b2 = *(const nf4*)&bx[2][4 * j];
#pragma unroll
            for (int a = 0; a < 4; ++a) {
                float sm = acc[a][p];
                sm = fmaf(wv[0][a], b0[0], sm);
                sm = fmaf(wv[1][a], b0[1], sm);
                sm = fmaf(wv[2][a], b0[2], sm);
                sm = fmaf(wv[3][a], b1[0], sm);
                sm = fmaf(wv[4][a], b1[1], sm);
                sm = fmaf(wv[5][a], b1[2], sm);
                sm = fmaf(wv[6][a], b2[0], sm);
                sm = fmaf(wv[7][a], b2[1], sm);
                sm = fmaf(wv[8][a], b2[2], sm);
                acc[a][p] = sm;
            }
        }
    }

    float* dst = part + (size_t)split * 524288;
#pragma unroll
    for (int a = 0; a < 4; ++a) {
        int c = 4 * cg + a;
        float* row = dst + (size_t)c * 4096 + i * 64 + 8 * pg;
        float4 lo = make_float4(acc[a][0], acc[a][1], acc[a][2], acc[a][3]);
        float4 hi = make_float4(acc[a][4], acc[a][5], acc[a][6], acc[a][7]);
        *(float4*)(row)     = lo;
        *(float4*)(row + 4) = hi;
    }
}

__global__ __launch_bounds__(256) void k_avgfin(const float* __restrict__ part,
                                                const float* __restrict__ bias,
                                                float* __restrict__ avg) {
    int idx4 = blockIdx.x * 256 + threadIdx.x;         // < 131072 float4s
    int c = idx4 >> 10;
    nf4 s = {0.f, 0.f, 0.f, 0.f};
#pragma unroll
    for (int sp = 0; sp < NSPLIT; ++sp)
        s += *(const nf4*)(part + (size_t)sp * 524288 + (size_t)idx4 * 4);
    nf4 o = s * 0.0625f + bias[c];
    *(nf4*)(avg + (size_t)idx4 * 4) = o;
}

// Block covers 1024 consecutive float4s of `final` (j, c block-uniform -> scalar loc).
// Per thread: 4 nt loads -> ROI adds -> 16 nt stores grouped by copy b.
__global__ __launch_bounds__(256) void k_out(const float* __restrict__ tissue,
                                             const float* __restrict__ avg,
                                             const int* __restrict__ loc,
                                             float* __restrict__ out) {
    int bid = blockIdx.x, tid = threadIdx.x;
    int base4 = bid * 1024;                            // first float4 index of this block
    int j = base4 >> 21;                               // block-uniform -> s_load
    int c = (base4 >> 14) & 127;                       // block-uniform
    int sh = (loc[2 * j + 1] >> 2) - 32;
    int sw = (loc[2 * j]     >> 2) - 32;
    const float* ar0 = avg + c * 4096;

    nf4 v[4];
    size_t f[4];
#pragma unroll
    for (int u = 0; u < 4; ++u) {
        int idx4 = base4 + u * 256 + tid;
        f[u] = (size_t)idx4 * 4;
        v[u] = __builtin_nontemporal_load((const nf4*)(tissue + f[u]));
    }
#pragma unroll
    for (int u = 0; u < 4; ++u) {
        int idx4 = base4 + u * 256 + tid;
        int h  = (idx4 >> 6) & 255;
        int ah = h - sh;
        if ((unsigned)ah < 64u) {
            const float* ar = ar0 + ah * 64;
            int aw = ((idx4 & 63) << 2) - sw;
            if ((unsigned)(aw    ) < 64u) v[u][0] += ar[aw];
            if ((unsigned)(aw + 1) < 64u) v[u][1] += ar[aw + 1];
            if ((unsigned)(aw + 2) < 64u) v[u][2] += ar[aw + 2];
            if ((unsigned)(aw + 3) < 64u) v[u][3] += ar[aw + 3];
        }
    }
#pragma unroll
    for (int b = 0; b < 4; ++b) {
        float* outb = out + (size_t)b * 33554432;
#pragma unroll
        for (int u = 0; u < 4; ++u)
            __builtin_nontemporal_store(v[u], (nf4*)(outb + f[u]));
    }
}

extern "C" void kernel_launch(void* const* d_in, const int* in_sizes, int n_in,
                              void* d_out, int out_size, void* d_ws, size_t ws_size,
                              hipStream_t stream) {
    const float* tissue = (const float*)d_in[0];
    const float* cell   = (const float*)d_in[1];
    const int*   loc    = (const int*)d_in[2];
    const float* w      = (const float*)d_in[3];
    const float* bias   = (const float*)d_in[4];
    float* out = (float*)d_out;

    char* wsb = (char*)d_ws;
    float* part = (float*)(wsb);
    float* avg  = (float*)(wsb + 33554432);
    float* wT2  = (float*)(wsb + 35651584);

    k_wt<<<576, 256, 0, stream>>>(w, wT2);
    k_gemm<<<dim3(64, NSPLIT), 256, 0, stream>>>(cell, wT2, part);
    k_avgfin<<<512, 256, 0, stream>>>(part, bias, avg);
    k_out<<<8192, 256, 0, stream>>>(tissue, avg, loc, out);
}

// Round 8
// 186.304 us; speedup vs baseline: 1.1381x; 1.0150x over previous
//
#include <hip/hip_runtime.h>

typedef float nf4 __attribute__((ext_vector_type(4)));

// Cell2Tissue: conv3x3(cell) -> avgpool4 -> add into per-sample ROI of tissue -> broadcast x4.
//
// Pipeline (4 kernels):
//  k_wt    : wT2[ci][k][c] = w[c][ci][k]   (590 KB, once)
//  k_gemm  : per (pooled-row i, split): 6 cell rows -> vertical 4-sums -> box row-triple in
//            LDS -> FMA vs coalesced-staged wT2 slice. part[s][c][i*64+j].
//  k_avgfin: avg = bias + (sum_s part[s]) / 16
//  k_out   : read-once-write-4: 1 float4/thread, 4 PLAIN stores (L2 write-combining;
//            nt stores measured 4.45 TB/s vs 6.29 TB/s m13 copy -> testing allocating stores)
//
// ws layout (bytes): part @0 (33,554,432) | avg @33,554,432 (2,097,152) | wT2 @35,651,584 (589,824)

#define NSPLIT 16
#define CIPS   8          // input channels per split

__global__ __launch_bounds__(256) void k_wt(const float* __restrict__ w,
                                            float* __restrict__ wT2) {
    int idx = blockIdx.x * 256 + threadIdx.x;          // 147456 = 128ci * 9k * 128c
    int c  = idx & 127;
    int k  = (idx >> 7) % 9;
    int ci = idx / 1152;
    wT2[idx] = w[(size_t)c * 1152 + ci * 9 + k];
}

__global__ __launch_bounds__(256) void k_gemm(const float* __restrict__ cell,
                                              const float* __restrict__ wT2,
                                              float* __restrict__ part) {
    __shared__ float vs[3][260];   // vertical 4-sums; index = cell col + 1 (cols -1..257)
    __shared__ float bx[3][256];   // box rows yy = 4i+dy
    __shared__ float wl[1152];     // wl[k*128 + c] = w[c][ci][k]
    int i     = blockIdx.x;        // pooled row 0..63
    int split = blockIdx.y;        // 0..15
    int tid = threadIdx.x;
    int cg  = tid & 31;            // out-channel group: c = 4*cg + a
    int pg  = tid >> 5;            // position group: j = 8*pg + p

    if (tid < 9) {                 // zero halo slots of vs once
        int dy = tid / 3, q = tid % 3;
        vs[dy][q == 0 ? 0 : 256 + q] = 0.f;   // slots 0, 257, 258
    }

    float acc[4][8];
#pragma unroll
    for (int a = 0; a < 4; ++a)
#pragma unroll
        for (int p = 0; p < 8; ++p) acc[a][p] = 0.f;

    int r0 = 4 * i - 1;
    for (int t = 0; t < CIPS; ++t) {
        int ci = split * CIPS + t;
        const float* base = cell + (size_t)ci * 65536;
        float cr[6];
#pragma unroll
        for (int r = 0; r < 6; ++r) {
            int row = r0 + r;
            cr[r] = ((unsigned)row < 256u) ? base[row * 256 + tid] : 0.f;
        }
        __syncthreads();                       // prior iter done reading wl / vs
        vs[0][tid + 1] = cr[0] + cr[1] + cr[2] + cr[3];
        vs[1][tid + 1] = cr[1] + cr[2] + cr[3] + cr[4];
        vs[2][tid + 1] = cr[2] + cr[3] + cr[4] + cr[5];
        const float* wsrc = wT2 + (size_t)ci * 1152;   // coalesced, L2-resident
#pragma unroll
        for (int s = 0; s < 5; ++s) {
            int q = tid + 256 * s;
            if (q < 1152) wl[q] = wsrc[q];
        }
        __syncthreads();                       // vs + wl visible
#pragma unroll
        for (int dy = 0; dy < 3; ++dy)
            bx[dy][tid] = vs[dy][tid] + vs[dy][tid + 1] + vs[dy][tid + 2] + vs[dy][tid + 3];
        __syncthreads();                       // bx visible

        nf4 wv[9];
#pragma unroll
        for (int k = 0; k < 9; ++k)
            wv[k] = *(const nf4*)&wl[k * 128 + 4 * cg];
#pragma unroll
        for (int p = 0; p < 8; ++p) {
            int j = 8 * pg + p;
            nf4 b0 = *(const nf4*)&bx[0][4 * j];
            nf4 b1 = *(const nf4*)&bx[1][4 * j];
            nf4 b2 = *(const nf4*)&bx[2][4 * j];
#pragma unroll
            for (int a = 0; a < 4; ++a) {
                float sm = acc[a][p];
                sm = fmaf(wv[0][a], b0[0], sm);
                sm = fmaf(wv[1][a], b0[1], sm);
                sm = fmaf(wv[2][a], b0[2], sm);
                sm = fmaf(wv[3][a], b1[0], sm);
                sm = fmaf(wv[4][a], b1[1], sm);
                sm = fmaf(wv[5][a], b1[2], sm);
                sm = fmaf(wv[6][a], b2[0], sm);
                sm = fmaf(wv[7][a], b2[1], sm);
                sm = fmaf(wv[8][a], b2[2], sm);
                acc[a][p] = sm;
            }
        }
    }

    float* dst = part + (size_t)split * 524288;
#pragma unroll
    for (int a = 0; a < 4; ++a) {
        int c = 4 * cg + a;
        float* row = dst + (size_t)c * 4096 + i * 64 + 8 * pg;
        float4 lo = make_float4(acc[a][0], acc[a][1], acc[a][2], acc[a][3]);
        float4 hi = make_float4(acc[a][4], acc[a][5], acc[a][6], acc[a][7]);
        *(float4*)(row)     = lo;
        *(float4*)(row + 4) = hi;
    }
}

__global__ __launch_bounds__(256) void k_avgfin(const float* __restrict__ part,
                                                const float* __restrict__ bias,
                                                float* __restrict__ avg) {
    int idx4 = blockIdx.x * 256 + threadIdx.x;         // < 131072 float4s
    int c = idx4 >> 10;
    nf4 s = {0.f, 0.f, 0.f, 0.f};
#pragma unroll
    for (int sp = 0; sp < NSPLIT; ++sp)
        s += *(const nf4*)(part + (size_t)sp * 524288 + (size_t)idx4 * 4);
    nf4 o = s * 0.0625f + bias[c];
    *(nf4*)(avg + (size_t)idx4 * 4) = o;
}

// 1 float4/thread; j, c block-uniform -> scalar loc; 4 allocating stores.
__global__ __launch_bounds__(256) void k_out(const float* __restrict__ tissue,
                                             const float* __restrict__ avg,
                                             const int* __restrict__ loc,
                                             float* __restrict__ out) {
    int idx4 = blockIdx.x * 256 + threadIdx.x;         // < 8,388,608 float4s of `final`
    size_t f = (size_t)idx4 * 4;
    int j = blockIdx.x >> 13;                          // block-uniform -> s_load
    int c = (blockIdx.x >> 6) & 127;                   // block-uniform
    int sh = (loc[2 * j + 1] >> 2) - 32;
    int sw = (loc[2 * j]     >> 2) - 32;

    nf4 v = __builtin_nontemporal_load((const nf4*)(tissue + f));

    int h  = (idx4 >> 6) & 255;
    int ah = h - sh;
    if ((unsigned)ah < 64u) {
        const float* ar = avg + c * 4096 + ah * 64;
        int aw = ((idx4 & 63) << 2) - sw;
        if ((unsigned)(aw    ) < 64u) v[0] += ar[aw];
        if ((unsigned)(aw + 1) < 64u) v[1] += ar[aw + 1];
        if ((unsigned)(aw + 2) < 64u) v[2] += ar[aw + 2];
        if ((unsigned)(aw + 3) < 64u) v[3] += ar[aw + 3];
    }
#pragma unroll
    for (int b = 0; b < 4; ++b)
        *(nf4*)(out + (size_t)b * 33554432 + f) = v;   // plain allocating store
}

extern "C" void kernel_launch(void* const* d_in, const int* in_sizes, int n_in,
                              void* d_out, int out_size, void* d_ws, size_t ws_size,
                              hipStream_t stream) {
    const float* tissue = (const float*)d_in[0];
    const float* cell   = (const float*)d_in[1];
    const int*   loc    = (const int*)d_in[2];
    const float* w      = (const float*)d_in[3];
    const float* bias   = (const float*)d_in[4];
    float* out = (float*)d_out;

    char* wsb = (char*)d_ws;
    float* part = (float*)(wsb);
    float* avg  = (float*)(wsb + 33554432);
    float* wT2  = (float*)(wsb + 35651584);

    k_wt<<<576, 256, 0, stream>>>(w, wT2);
    k_gemm<<<dim3(64, NSPLIT), 256, 0, stream>>>(cell, wT2, part);
    k_avgfin<<<512, 256, 0, stream>>>(part, bias, avg);
    k_out<<<32768, 256, 0, stream>>>(tissue, avg, loc, out);
}